// Round 7
// baseline (248.510 us; speedup 1.0000x reference)
//
#include <hip/hip_runtime.h>
#include <math.h>

// MoE top-2 router. Round 10: barrier-free TLP GEMV + in-block K-split.
// Six rounds of evidence: every per-chunk-barrier pipeline (any vmcnt
// discipline) lands 80-104us -- the 4-wave rendezvous IS the stall. The
// R5-verified direct-to-register MFMA fragments need no LDS and no barriers;
// they only failed at 1 wave/SIMD. Fix: in-block K-split. Block = 16 tokens,
// 4 waves; wave wv computes all 64 experts over k-quarter wv*512..+512 with
// loads straight from global (x: 32B/lane of its token row; W: 16B/lane of
// its expert row, L2-hot). 4 blocks/CU x 4 waves = 4 waves/SIMD of
// independent TLP -- no prefetch choreography at all. One syncthreads at the
// end: exchange partial logits via 16KB LDS, sum 4 quarters, verified 64-lane
// softmax/top-2 epilogue. No P round-trip, no reduce kernel.
//
// x: [16384, 2048] fp32, W: [64, 2048] fp32.
// outputs (concat, fp32): mask [T,64], idx-as-float [T,2],
//                         router_probs [T,64], probs [T,64]

#define D_DIM 2048
#define E_DIM 64

typedef __bf16 bf16x8 __attribute__((ext_vector_type(8)));
typedef unsigned short us8 __attribute__((ext_vector_type(8)));
typedef float f32x4 __attribute__((ext_vector_type(4)));

static __device__ __forceinline__ unsigned short f2bf(float f) {
    unsigned int u = __float_as_uint(f);
    u += 0x7fffu + ((u >> 16) & 1u);   // RNE
    return (unsigned short)(u >> 16);
}
static __device__ __forceinline__ float bf2f(unsigned short h) {
    return __uint_as_float(((unsigned int)h) << 16);
}
static __device__ __forceinline__ void split4(const float4 v, ushort4* h, ushort4* l) {
    h->x = f2bf(v.x); l->x = f2bf(v.x - bf2f(h->x));
    h->y = f2bf(v.y); l->y = f2bf(v.y - bf2f(h->y));
    h->z = f2bf(v.z); l->z = f2bf(v.z - bf2f(h->z));
    h->w = f2bf(v.w); l->w = f2bf(v.w - bf2f(h->w));
}

// ---- pre-convert W (64x2048 fp32) -> bf16 hi/lo, linear layout ----
__global__ __launch_bounds__(256, 1) void convert_w(
    const float4* __restrict__ W4, unsigned short* __restrict__ WH,
    unsigned short* __restrict__ WL)
{
    int i = blockIdx.x * 256 + threadIdx.x;   // float4 index
    float4 v = W4[i];
    ushort4 h, l;
    split4(v, &h, &l);
    *(ushort4*)&WH[i * 4] = h;
    *(ushort4*)&WL[i * 4] = l;
}

// ---- fused GEMM + softmax + top-2 + outputs ----
// block = 16 tokens, 256 threads (4 waves); wave wv = k-quarter wv*512..+512,
// all 64 experts (acc[4] = 4 expert tiles of 16). R5-verified fragments:
// A: lane(l16,quad) = x[t0+l16][k + quad*8..+8]; B: W[n*16+l16][k+quad*8..+8].
__global__ __launch_bounds__(256, 4) void router_fused(
    const float* __restrict__ x,
    const unsigned short* __restrict__ WHg, const unsigned short* __restrict__ WLg,
    float* __restrict__ mask_out, float* __restrict__ idx_out,
    float* __restrict__ rp_out, float* __restrict__ probs_out)
{
    __shared__ __align__(16) float Lp[4][16 * 64];   // 16 KB partial logits

    const int tid  = threadIdx.x;
    const int lane = tid & 63;
    const int wv   = tid >> 6;          // k-quarter index
    const int quad = lane >> 4;
    const int l16  = lane & 15;
    const int t0   = blockIdx.x << 4;

    const int k0 = wv << 9;             // this wave's k-slice base (512 k)

    const float*          xp  = x   + (size_t)(t0 + l16) * D_DIM + k0 + quad * 8;
    const unsigned short* whp = WHg + (size_t)l16 * D_DIM + k0 + quad * 8;
    const unsigned short* wlp = WLg + (size_t)l16 * D_DIM + k0 + quad * 8;

    f32x4 acc[4];
    #pragma unroll
    for (int n = 0; n < 4; ++n) { f32x4 z = {0.f, 0.f, 0.f, 0.f}; acc[n] = z; }

    // ---- k-loop: 16 steps of 32, no barriers, loads direct from global ----
    #pragma unroll 2
    for (int j = 0; j < 16; ++j) {
        const int o = j << 5;                     // element offset in slice
        float4 xa = *(const float4*)(xp + o);
        float4 xb = *(const float4*)(xp + o + 4);
        ushort4 h0, l0, h1, l1;
        split4(xa, &h0, &l0);
        split4(xb, &h1, &l1);
        union { us8 u; bf16x8 b; } ua, ul;
        ua.u = (us8){h0.x, h0.y, h0.z, h0.w, h1.x, h1.y, h1.z, h1.w};
        ul.u = (us8){l0.x, l0.y, l0.z, l0.w, l1.x, l1.y, l1.z, l1.w};

        #pragma unroll
        for (int n = 0; n < 4; ++n) {
            bf16x8 bh = *(const bf16x8*)(whp + n * 16 * D_DIM + o);
            bf16x8 bl = *(const bf16x8*)(wlp + n * 16 * D_DIM + o);
            acc[n] = __builtin_amdgcn_mfma_f32_16x16x32_bf16(ua.b, bh, acc[n], 0, 0, 0);
            acc[n] = __builtin_amdgcn_mfma_f32_16x16x32_bf16(ul.b, bh, acc[n], 0, 0, 0);
            acc[n] = __builtin_amdgcn_mfma_f32_16x16x32_bf16(ua.b, bl, acc[n], 0, 0, 0);
        }
    }

    // ---- exchange partials: acc[n][r] = partial logit of
    // (token quad*4+r, expert n*16+l16) for k-quarter wv ----
    #pragma unroll
    for (int n = 0; n < 4; ++n)
        #pragma unroll
        for (int r = 0; r < 4; ++r)
            Lp[wv][(quad * 4 + r) * 64 + n * 16 + l16] = acc[n][r];
    __syncthreads();

    // ---- verified 64-lane softmax / top-2 / writeout; wave per 4 tokens ----
    for (int i = 0; i < 4; ++i) {
        const int tl = wv * 4 + i;              // token within block
        const int t  = t0 + tl;
        const float v = Lp[0][tl * 64 + lane] + Lp[1][tl * 64 + lane]
                      + Lp[2][tl * 64 + lane] + Lp[3][tl * 64 + lane];

        // argmax, lower-index tie-break (matches jax.lax.top_k)
        float bv = v; int bi = lane;
        #pragma unroll
        for (int off = 1; off < 64; off <<= 1) {
            float ov = __shfl_xor(bv, off, 64);
            int   oi = __shfl_xor(bi, off, 64);
            bool take = (ov > bv) || (ov == bv && oi < bi);
            bv = take ? ov : bv;
            bi = take ? oi : bi;
        }
        const float m = bv; const int i1 = bi;

        const float p = __expf(v - m);
        float s = p;
        #pragma unroll
        for (int off = 1; off < 64; off <<= 1) s += __shfl_xor(s, off, 64);
        const float prob = p / s;

        // second argmax excluding i1
        const float v2 = (lane == i1) ? -INFINITY : v;
        float cv = v2; int ci = lane;
        #pragma unroll
        for (int off = 1; off < 64; off <<= 1) {
            float ov = __shfl_xor(cv, off, 64);
            int   oi = __shfl_xor(ci, off, 64);
            bool take = (ov > cv) || (ov == cv && oi < ci);
            cv = take ? ov : cv;
            ci = take ? oi : ci;
        }
        const int i2 = ci;

        const float pd = __shfl(prob, i1, 64) + __shfl(prob, i2, 64);
        const bool top = (lane == i1) || (lane == i2);

        const size_t base = (size_t)t * 64 + lane;
        mask_out[base]  = top ? 1.f : 0.f;
        rp_out[base]    = top ? prob / pd : 0.f;
        probs_out[base] = prob;
        if (lane == 0) {
            idx_out[(size_t)t * 2]     = (float)i1;
            idx_out[(size_t)t * 2 + 1] = (float)i2;
        }
    }
}

extern "C" void kernel_launch(void* const* d_in, const int* in_sizes, int n_in,
                              void* d_out, int out_size, void* d_ws, size_t ws_size,
                              hipStream_t stream) {
    const float* x = (const float*)d_in[0];
    const float* W = (const float*)d_in[1];
    float* out = (float*)d_out;

    const int T  = in_sizes[0] / D_DIM;     // 16384 tokens
    const int WN = in_sizes[1];             // 131072 elements

    unsigned short* WH = (unsigned short*)d_ws;
    unsigned short* WL = WH + WN;           // total ws use: 512 KB

    float* mask_out  = out;
    float* idx_out   = out + (size_t)T * E_DIM;
    float* rp_out    = idx_out + (size_t)T * 2;
    float* probs_out = rp_out + (size_t)T * E_DIM;

    convert_w<<<dim3(WN / 1024), dim3(256), 0, stream>>>((const float4*)W, WH, WL);
    router_fused<<<dim3(T / 16), dim3(256), 0, stream>>>(
        x, WH, WL, mask_out, idx_out, rp_out, probs_out);
}